// Round 1
// baseline (2596.314 us; speedup 1.0000x reference)
//
#include <hip/hip_runtime.h>
#include <hip/hip_bf16.h>
#include <math.h>

// Round 3: 512 blocks x 16 rows (2 blocks/CU for barrier/latency overlap),
// halved accumulator footprint, shared 32-bit weight offsets, interleaved
// token table (float2 rz + float n, b_hh0 folded), cvt_pk_bf16 h-writeback.

#define BATCH 8192
#define TTOT 50
#define TS 49
#define HID 256
#define N3 768
#define VOCAB 148
#define START_TOK 1
#define HPAD 264

typedef short bf16x8 __attribute__((ext_vector_type(8)));
typedef float f32x4 __attribute__((ext_vector_type(4)));

// ---- workspace layout (bytes) ----
constexpr size_t OFF_Y    = 0;                        // 49*8192*256*2 (packed)
constexpr size_t OFF_WH0B = OFF_Y + 205520896;        // 768*256*2 packed
constexpr size_t OFF_WI1B = OFF_WH0B + 393216;
constexpr size_t OFF_WH1B = OFF_WI1B + 393216;
constexpr size_t OFF_W1B  = OFF_WH1B + 393216;        // 256*256*2 packed
constexpr size_t OFF_W2B  = OFF_W1B + 131072;         // 160*256*2 packed (rows >=148 zero)
constexpr size_t OFF_TAB  = OFF_W2B + 81920;          // tab_rz 148*256*2*4 = 303104
constexpr size_t OFF_TABN = OFF_TAB + 303104;         // tab_n  148*256*4   = 151552
constexpr size_t OFF_H0F  = OFF_TAB + 454656;         // 8192*256*4
constexpr size_t OFF_H1F  = OFF_H0F + 8388608;

__device__ __forceinline__ short f2b(float f) {
    union { float f; unsigned int u; } v; v.f = f;
    unsigned int u = v.u;
    return (short)((u + 0x7FFFu + ((u >> 16) & 1u)) >> 16);
}
// clamp-free: inf semantics give correct limits (exp(+inf)->inf, rcp(inf)->0)
__device__ __forceinline__ float sigm(float x) {
    return 1.f / (1.f + __expf(-x));
}
__device__ __forceinline__ float tanh_(float x) {
    x = fmaxf(x, -15.f);                 // only the NaN-producing side needs a guard
    float e = __expf(-2.f * x);
    return (1.f - e) / (1.f + e);
}

// ---- convert + swizzle weights into fragment order P[nt][kc][lane][8] ----
__global__ __launch_bounds__(256) void convert_w(
    const float* __restrict__ Wh0, const float* __restrict__ Wi1, const float* __restrict__ Wh1,
    const float* __restrict__ W1, const float* __restrict__ W2,
    short* __restrict__ Wh0b, short* __restrict__ Wi1b, short* __restrict__ Wh1b,
    short* __restrict__ W1b, short* __restrict__ W2b)
{
    int tid = blockIdx.x * 256 + threadIdx.x;
    const int WSZ = N3 * HID; // 196608
    const float* S; short* D; int n; bool pad148 = false;
    if (tid < WSZ) { S = Wh0; D = Wh0b; n = tid; }
    else if (tid < 2 * WSZ) { S = Wi1; D = Wi1b; n = tid - WSZ; }
    else if (tid < 3 * WSZ) { S = Wh1; D = Wh1b; n = tid - 2 * WSZ; }
    else if (tid < 3 * WSZ + 65536) { S = W1; D = W1b; n = tid - 3 * WSZ; }
    else if (tid < 3 * WSZ + 65536 + 40960) { S = W2; D = W2b; n = tid - 3 * WSZ - 65536; pad148 = true; }
    else return;
    int e = n & 7, lane = (n >> 3) & 63, kc = (n >> 9) & 7, nt = n >> 12;
    int row = nt * 16 + (lane & 15);
    int k = kc * 32 + (lane >> 4) * 8 + e;
    float v = (pad148 && row >= VOCAB) ? 0.f : S[row * HID + k];
    D[n] = f2b(v);
}

// ---- token table, interleaved:
//   tab_rz[v][c] = { bih0[c]+bhh0[c]+emb.Wih0[c],  bih0[256+c]+bhh0[256+c]+emb.Wih0[256+c] }
//   tab_n [v][c] =   bih0[512+c]+emb.Wih0[512+c]
__global__ __launch_bounds__(256) void build_tab2(
    const float* __restrict__ emb, const float* __restrict__ Wih0,
    const float* __restrict__ bih0, const float* __restrict__ bhh0,
    float* __restrict__ tab_rz, float* __restrict__ tab_n)
{
    int o = blockIdx.x * 256 + threadIdx.x;
    if (o >= VOCAB * N3) return;
    int v = o / N3, cc = o - v * N3;
    int g = cc >> 8, c = cc & 255;
    const float* er = emb + v * HID;
    const float* wr = Wih0 + cc * HID;
    float s = bih0[cc];
    #pragma unroll 8
    for (int k = 0; k < HID; ++k) s += er[k] * wr[k];
    if (g == 0)      tab_rz[(((v << 8) + c) << 1) + 0] = s + bhh0[c];
    else if (g == 1) tab_rz[(((v << 8) + c) << 1) + 1] = s + bhh0[256 + c];
    else             tab_n[(v << 8) + c] = s;
}

// ---- h_init = z @ W_lat.T + b_lat (fp32) ----
__global__ __launch_bounds__(256) void init_h(
    const float* __restrict__ z, const float* __restrict__ Wl, const float* __restrict__ bl,
    float* __restrict__ h0f, float* __restrict__ h1f)
{
    int tid = blockIdx.x * 256 + threadIdx.x;   // b*512 + o
    int b = tid >> 9, o = tid & 511;
    const float* zr = z + b * 32;
    const float* wr = Wl + o * 32;
    float s = bl[o];
    #pragma unroll
    for (int k = 0; k < 32; ++k) s += zr[k] * wr[k];
    if (o < HID) h0f[b * HID + o] = s;
    else         h1f[b * HID + o - HID] = s;
}

// ---- persistent recurrence: 512 blocks x 16 batch rows, 49 steps ----
__global__ __launch_bounds__(512, 4) void gru_persistent(
    const int* __restrict__ toks,
    const float* __restrict__ tab_rz, const float* __restrict__ tab_n,
    const short* __restrict__ Wh0, const short* __restrict__ Wi1, const short* __restrict__ Wh1,
    const float* __restrict__ bhh0, const float* __restrict__ bih1, const float* __restrict__ bhh1,
    const float* __restrict__ h0f, const float* __restrict__ h1f,
    short* __restrict__ Yb)
{
    __shared__ short h0L[16 * HPAD];
    __shared__ short h1L[16 * HPAD];
    __shared__ int tokL[16 * TTOT];

    const int tid = threadIdx.x;
    const int wave = tid >> 6, lane = tid & 63, quad = lane >> 4, l15 = lane & 15;
    const int rowbase = blockIdx.x * 16;

    // --- stage LDS h (bf16) + tokens ---
    {
        int row = tid >> 5, col = (tid & 31) * 8;        // 512 chunks exactly
        const float* s0 = h0f + (size_t)(rowbase + row) * HID + col;
        const float* s1 = h1f + (size_t)(rowbase + row) * HID + col;
        short t0[8], t1[8];
        #pragma unroll
        for (int j = 0; j < 8; ++j) { t0[j] = f2b(s0[j]); t1[j] = f2b(s1[j]); }
        *(bf16x8*)&h0L[row * HPAD + col] = *(bf16x8*)t0;
        *(bf16x8*)&h1L[row * HPAD + col] = *(bf16x8*)t1;
    }
    for (int idx = tid; idx < 16 * TTOT; idx += 512) {
        int row = idx / TTOT, tt = idx - row * TTOT;
        tokL[idx] = (tt == 0) ? START_TOK : toks[(size_t)(rowbase + row) * TTOT + tt];
    }

    // fp32 h carry in registers (C-layout: row quad*4+r, col wave*32+c*16+l15)
    int colc[2]; colc[0] = wave * 32 + l15; colc[1] = colc[0] + 16;
    float h0r[2][4], h1r[2][4];
    #pragma unroll
    for (int c = 0; c < 2; ++c)
        #pragma unroll
        for (int r_ = 0; r_ < 4; ++r_) {
            int row = rowbase + quad * 4 + r_;
            h0r[c][r_] = h0f[(size_t)row * HID + colc[c]];
            h1r[c][r_] = h1f[(size_t)row * HID + colc[c]];
        }

    // hoisted per-thread biases (t-invariant)
    float bn0[2], brr[2], brz[2], bni[2], bnh[2];
    #pragma unroll
    for (int c = 0; c < 2; ++c) {
        int col = colc[c];
        bn0[c] = bhh0[512 + col];
        brr[c] = bih1[col] + bhh1[col];
        brz[c] = bih1[256 + col] + bhh1[256 + col];
        bni[c] = bih1[512 + col];
        bnh[c] = bhh1[512 + col];
    }

    // shared 32-bit weight offsets (same for Wh0/Wh1/Wi1), j = gate*2 + half
    int woff[6];
    #pragma unroll
    for (int g = 0; g < 3; ++g)
        #pragma unroll
        for (int c = 0; c < 2; ++c)
            woff[g * 2 + c] = ((g * 16 + wave * 2 + c) << 12) + lane * 8;

    const int a0base = l15 * HPAD + quad * 8;            // A-frag LDS base (shorts)
    const int hwbase = (quad * 4) * HPAD + colc[0];      // h-write base (shorts)
    int tokrow[4];
    #pragma unroll
    for (int r_ = 0; r_ < 4; ++r_) tokrow[r_] = (quad * 4 + r_) * TTOT;
    short* yptr = Yb + ((((size_t)blockIdx.x << 3) + wave) << 9) + lane * 8;

    __syncthreads();

    for (int t = 0; t < TS; ++t) {
        // ---- merged kloop: gh0 (h0 @ Wh0.T) and gh1 (h1 @ Wh1.T) ----
        f32x4 acc0[6] = {};
        f32x4 accrz[4] = {}, acchn[2] = {};
        #pragma unroll 2
        for (int kc = 0; kc < 8; ++kc) {
            bf16x8 a0 = *(const bf16x8*)&h0L[a0base + kc * 32];
            bf16x8 a1 = *(const bf16x8*)&h1L[a0base + kc * 32];
            #pragma unroll
            for (int j = 0; j < 6; ++j) {
                bf16x8 b0 = *(const bf16x8*)(Wh0 + woff[j] + kc * 512);
                acc0[j] = __builtin_amdgcn_mfma_f32_16x16x32_bf16(a0, b0, acc0[j], 0, 0, 0);
            }
            #pragma unroll
            for (int j = 0; j < 6; ++j) {
                bf16x8 b1 = *(const bf16x8*)(Wh1 + woff[j] + kc * 512);
                if (j < 4) accrz[j] = __builtin_amdgcn_mfma_f32_16x16x32_bf16(a1, b1, accrz[j], 0, 0, 0);
                else       acchn[j - 4] = __builtin_amdgcn_mfma_f32_16x16x32_bf16(a1, b1, acchn[j - 4], 0, 0, 0);
            }
        }
        // ---- layer-0 gates (gi0 from interleaved token table) ----
        #pragma unroll
        for (int r_ = 0; r_ < 4; ++r_) {
            int tok = tokL[tokrow[r_] + t];
            const float2 rz0 = *(const float2*)(tab_rz + (tok << 9) + (colc[0] << 1));
            const float2 rz1 = *(const float2*)(tab_rz + (tok << 9) + (colc[1] << 1));
            float in0 = tab_n[(tok << 8) + colc[0]];
            float in1 = tab_n[(tok << 8) + colc[1]];
            {
                float r = sigm(acc0[0][r_] + rz0.x);
                float z = sigm(acc0[2][r_] + rz0.y);
                float n = tanh_(in0 + r * (acc0[4][r_] + bn0[0]));
                h0r[0][r_] = n + z * (h0r[0][r_] - n);
            }
            {
                float r = sigm(acc0[1][r_] + rz1.x);
                float z = sigm(acc0[3][r_] + rz1.y);
                float n = tanh_(in1 + r * (acc0[5][r_] + bn0[1]));
                h0r[1][r_] = n + z * (h0r[1][r_] - n);
            }
        }
        __syncthreads();   // all waves done reading h0L/h1L
        #pragma unroll
        for (int r_ = 0; r_ < 4; ++r_) {
            unsigned u;
            asm("v_cvt_pk_bf16_f32 %0, %1, %2" : "=v"(u) : "v"(h0r[0][r_]), "v"(h0r[1][r_]));
            int ro = hwbase + r_ * HPAD;
            h0L[ro]      = (short)u;
            h0L[ro + 16] = (short)(u >> 16);
        }
        __syncthreads();   // h0n visible to all

        // ---- kloop gi1 = h0n @ Wi1.T (rz on top of gh1-rz, n separate) ----
        f32x4 accgn[2] = {};
        #pragma unroll 2
        for (int kc = 0; kc < 8; ++kc) {
            bf16x8 a = *(const bf16x8*)&h0L[a0base + kc * 32];
            #pragma unroll
            for (int j = 0; j < 6; ++j) {
                bf16x8 b = *(const bf16x8*)(Wi1 + woff[j] + kc * 512);
                if (j < 4) accrz[j] = __builtin_amdgcn_mfma_f32_16x16x32_bf16(a, b, accrz[j], 0, 0, 0);
                else       accgn[j - 4] = __builtin_amdgcn_mfma_f32_16x16x32_bf16(a, b, accgn[j - 4], 0, 0, 0);
            }
        }
        // ---- layer-1 gates ----
        #pragma unroll
        for (int c = 0; c < 2; ++c)
            #pragma unroll
            for (int r_ = 0; r_ < 4; ++r_) {
                float r = sigm(accrz[c][r_] + brr[c]);
                float z = sigm(accrz[2 + c][r_] + brz[c]);
                float n = tanh_(accgn[c][r_] + bni[c] + r * (acchn[c][r_] + bnh[c]));
                h1r[c][r_] = n + z * (h1r[c][r_] - n);
            }
        #pragma unroll
        for (int r_ = 0; r_ < 4; ++r_) {
            unsigned u;
            asm("v_cvt_pk_bf16_f32 %0, %1, %2" : "=v"(u) : "v"(h1r[0][r_]), "v"(h1r[1][r_]));
            int ro = hwbase + r_ * HPAD;
            h1L[ro]      = (short)u;
            h1L[ro + 16] = (short)(u >> 16);
        }
        __syncthreads();   // h1n visible

        // ---- packed Y[t] write: wave w stores kc=w (one 1KB coalesced store) ----
        *(bf16x8*)yptr = *(const bf16x8*)&h1L[a0base + wave * 32];
        yptr += (size_t)512 * 8 * 512;
        // no extra barrier: next h0L/h1L writes are behind the next barriers
    }
}

// ---- fused head: hdd = relu(Y@W1.T+b1) in LDS, logits = hdd@W2.T+b2 ----
__global__ __launch_bounds__(256) void head_kernel(
    const short* __restrict__ YP, const short* __restrict__ W1P, const float* __restrict__ b1,
    const short* __restrict__ W2P, const float* __restrict__ b2, float* __restrict__ out)
{
    __shared__ short hddL[64 * HPAD];
    int wave = threadIdx.x >> 6;
    int lane = threadIdx.x & 63;
    int quad = lane >> 4;
    int l15  = lane & 15;
    int rbase = blockIdx.x * 64;
    int tt = rbase >> 13;                 // time index (rows = t*8192 + b)
    int mb = (rbase & 8191) >> 4;         // 16-row tile base within t

    { // stage A: hdd tile 64x256; wave w owns n-tiles [w*4, w*4+4)
        const short* ybase = YP + ((size_t)tt * 512 + mb) * 4096 + lane * 8;
        const short* wbase = W1P + (size_t)(wave * 4) * 4096 + lane * 8;
        f32x4 acc[4][4] = {};
        #pragma unroll 2
        for (int kc = 0; kc < 8; ++kc) {
            bf16x8 a[4], bfr[4];
            #pragma unroll
            for (int i = 0; i < 4; ++i) a[i] = *(const bf16x8*)(ybase + (size_t)i * 4096 + kc * 512);
            #pragma unroll
            for (int j = 0; j < 4; ++j) bfr[j] = *(const bf16x8*)(wbase + (size_t)j * 4096 + kc * 512);
            #pragma unroll
            for (int i = 0; i < 4; ++i)
                #pragma unroll
                for (int j = 0; j < 4; ++j)
                    acc[i][j] = __builtin_amdgcn_mfma_f32_16x16x32_bf16(a[i], bfr[j], acc[i][j], 0, 0, 0);
        }
        #pragma unroll
        for (int i = 0; i < 4; ++i)
            #pragma unroll
            for (int j = 0; j < 4; ++j)
                #pragma unroll
                for (int r = 0; r < 4; ++r) {
                    int rl = i * 16 + quad * 4 + r;
                    int c  = wave * 64 + j * 16 + l15;
                    float v = acc[i][j][r] + b1[c];
                    hddL[rl * HPAD + c] = f2b(fmaxf(v, 0.f));
                }
    }
    __syncthreads();
    // stage B: 20 subtiles (10 col-tiles x 2 row-halves) / 4 waves
    for (int s = wave * 5; s < wave * 5 + 5; ++s) {
        int ct = s >> 1, rh = s & 1;
        const short* w2b = W2P + (size_t)ct * 4096 + lane * 8;
        f32x4 acc2[2] = {};
        #pragma unroll 2
        for (int kc = 0; kc < 8; ++kc) {
            bf16x8 bfr = *(const bf16x8*)(w2b + kc * 512);
            #pragma unroll
            for (int it = 0; it < 2; ++it) {
                bf16x8 a = *(const bf16x8*)&hddL[(rh * 32 + it * 16 + l15) * HPAD + kc * 32 + quad * 8];
                acc2[it] = __builtin_amdgcn_mfma_f32_16x16x32_bf16(a, bfr, acc2[it], 0, 0, 0);
            }
        }
        int col = ct * 16 + l15;
        if (col < VOCAB) {
            #pragma unroll
            for (int it = 0; it < 2; ++it)
                #pragma unroll
                for (int r = 0; r < 4; ++r) {
                    int rl = rh * 32 + it * 16 + quad * 4 + r;
                    int gr = rbase + rl;
                    int t2 = gr >> 13;
                    int bb = gr & 8191;
                    out[((size_t)bb * TS + t2) * VOCAB + col] = acc2[it][r] + b2[col];
                }
        }
    }
}

// ---- generated = target_tokens[:,1:] as float ----
__global__ __launch_bounds__(256) void gen_copy(const int* __restrict__ toks, float* __restrict__ out2)
{
    int tid = blockIdx.x * 256 + threadIdx.x;
    if (tid < BATCH * TS) {
        int b = tid / TS, j = tid - b * TS;
        out2[tid] = (float)toks[b * TTOT + j + 1];
    }
}

extern "C" void kernel_launch(void* const* d_in, const int* in_sizes, int n_in,
                              void* d_out, int out_size, void* d_ws, size_t ws_size,
                              hipStream_t stream) {
    const float* z     = (const float*)d_in[0];
    const int*   toks  = (const int*)d_in[1];
    const float* emb   = (const float*)d_in[2];
    const float* W_lat = (const float*)d_in[3];
    const float* b_lat = (const float*)d_in[4];
    const float* W_ih0 = (const float*)d_in[5];
    const float* W_hh0 = (const float*)d_in[6];
    const float* b_ih0 = (const float*)d_in[7];
    const float* b_hh0 = (const float*)d_in[8];
    const float* W_ih1 = (const float*)d_in[9];
    const float* W_hh1 = (const float*)d_in[10];
    const float* b_ih1 = (const float*)d_in[11];
    const float* b_hh1 = (const float*)d_in[12];
    const float* W1    = (const float*)d_in[13];
    const float* b1    = (const float*)d_in[14];
    const float* W2    = (const float*)d_in[15];
    const float* b2    = (const float*)d_in[16];

    char* w = (char*)d_ws;
    short* Yb    = (short*)(w + OFF_Y);
    short* Wh0b  = (short*)(w + OFF_WH0B);
    short* Wi1b  = (short*)(w + OFF_WI1B);
    short* Wh1b  = (short*)(w + OFF_WH1B);
    short* W1b   = (short*)(w + OFF_W1B);
    short* W2b   = (short*)(w + OFF_W2B);
    float* tabrz = (float*)(w + OFF_TAB);
    float* tabn  = (float*)(w + OFF_TABN);
    float* h0f   = (float*)(w + OFF_H0F);
    float* h1f   = (float*)(w + OFF_H1F);

    float* out_logits = (float*)d_out;
    float* out_gen    = out_logits + (size_t)BATCH * TS * VOCAB;

    convert_w<<<2720, 256, 0, stream>>>(W_hh0, W_ih1, W_hh1, W1, W2,
                                        Wh0b, Wi1b, Wh1b, W1b, W2b);
    build_tab2<<<(VOCAB * N3 + 255) / 256, 256, 0, stream>>>(emb, W_ih0, b_ih0, b_hh0, tabrz, tabn);
    init_h<<<(BATCH * 512) / 256, 256, 0, stream>>>(z, W_lat, b_lat, h0f, h1f);
    gen_copy<<<(BATCH * TS + 255) / 256, 256, 0, stream>>>(toks, out_gen);

    gru_persistent<<<512, 512, 0, stream>>>(toks, tabrz, tabn, Wh0b, Wi1b, Wh1b,
                                            b_hh0, b_ih1, b_hh1, h0f, h1f, Yb);

    head_kernel<<<(BATCH * TS) / 64, 256, 0, stream>>>(Yb, W1b, b1, W2b, b2, out_logits);
}

// Round 2
// 2119.213 us; speedup vs baseline: 1.2251x; 1.2251x over previous
//
#include <hip/hip_runtime.h>
#include <hip/hip_bf16.h>
#include <math.h>

// Round 4: identical to Round 3 EXCEPT __launch_bounds__(512, 2).
// R3's (512,4) acted as a 64-VGPR cap -> catastrophic scratch spill
// (FETCH 953MB, WRITE 819MB). (512,2) caps at 128 regs; the 16-row
// kernel needs ~120, so no spill, and grid=512 gives 2 blocks/CU.

#define BATCH 8192
#define TTOT 50
#define TS 49
#define HID 256
#define N3 768
#define VOCAB 148
#define START_TOK 1
#define HPAD 264

typedef short bf16x8 __attribute__((ext_vector_type(8)));
typedef float f32x4 __attribute__((ext_vector_type(4)));

// ---- workspace layout (bytes) ----
constexpr size_t OFF_Y    = 0;                        // 49*8192*256*2 (packed)
constexpr size_t OFF_WH0B = OFF_Y + 205520896;        // 768*256*2 packed
constexpr size_t OFF_WI1B = OFF_WH0B + 393216;
constexpr size_t OFF_WH1B = OFF_WI1B + 393216;
constexpr size_t OFF_W1B  = OFF_WH1B + 393216;        // 256*256*2 packed
constexpr size_t OFF_W2B  = OFF_W1B + 131072;         // 160*256*2 packed (rows >=148 zero)
constexpr size_t OFF_TAB  = OFF_W2B + 81920;          // tab_rz 148*256*2*4 = 303104
constexpr size_t OFF_TABN = OFF_TAB + 303104;         // tab_n  148*256*4   = 151552
constexpr size_t OFF_H0F  = OFF_TAB + 454656;         // 8192*256*4
constexpr size_t OFF_H1F  = OFF_H0F + 8388608;

__device__ __forceinline__ short f2b(float f) {
    union { float f; unsigned int u; } v; v.f = f;
    unsigned int u = v.u;
    return (short)((u + 0x7FFFu + ((u >> 16) & 1u)) >> 16);
}
// clamp-free: inf semantics give correct limits (exp(+inf)->inf, rcp(inf)->0)
__device__ __forceinline__ float sigm(float x) {
    return 1.f / (1.f + __expf(-x));
}
__device__ __forceinline__ float tanh_(float x) {
    x = fmaxf(x, -15.f);                 // only the NaN-producing side needs a guard
    float e = __expf(-2.f * x);
    return (1.f - e) / (1.f + e);
}

// ---- convert + swizzle weights into fragment order P[nt][kc][lane][8] ----
__global__ __launch_bounds__(256) void convert_w(
    const float* __restrict__ Wh0, const float* __restrict__ Wi1, const float* __restrict__ Wh1,
    const float* __restrict__ W1, const float* __restrict__ W2,
    short* __restrict__ Wh0b, short* __restrict__ Wi1b, short* __restrict__ Wh1b,
    short* __restrict__ W1b, short* __restrict__ W2b)
{
    int tid = blockIdx.x * 256 + threadIdx.x;
    const int WSZ = N3 * HID; // 196608
    const float* S; short* D; int n; bool pad148 = false;
    if (tid < WSZ) { S = Wh0; D = Wh0b; n = tid; }
    else if (tid < 2 * WSZ) { S = Wi1; D = Wi1b; n = tid - WSZ; }
    else if (tid < 3 * WSZ) { S = Wh1; D = Wh1b; n = tid - 2 * WSZ; }
    else if (tid < 3 * WSZ + 65536) { S = W1; D = W1b; n = tid - 3 * WSZ; }
    else if (tid < 3 * WSZ + 65536 + 40960) { S = W2; D = W2b; n = tid - 3 * WSZ - 65536; pad148 = true; }
    else return;
    int e = n & 7, lane = (n >> 3) & 63, kc = (n >> 9) & 7, nt = n >> 12;
    int row = nt * 16 + (lane & 15);
    int k = kc * 32 + (lane >> 4) * 8 + e;
    float v = (pad148 && row >= VOCAB) ? 0.f : S[row * HID + k];
    D[n] = f2b(v);
}

// ---- token table, interleaved:
//   tab_rz[v][c] = { bih0[c]+bhh0[c]+emb.Wih0[c],  bih0[256+c]+bhh0[256+c]+emb.Wih0[256+c] }
//   tab_n [v][c] =   bih0[512+c]+emb.Wih0[512+c]
__global__ __launch_bounds__(256) void build_tab2(
    const float* __restrict__ emb, const float* __restrict__ Wih0,
    const float* __restrict__ bih0, const float* __restrict__ bhh0,
    float* __restrict__ tab_rz, float* __restrict__ tab_n)
{
    int o = blockIdx.x * 256 + threadIdx.x;
    if (o >= VOCAB * N3) return;
    int v = o / N3, cc = o - v * N3;
    int g = cc >> 8, c = cc & 255;
    const float* er = emb + v * HID;
    const float* wr = Wih0 + cc * HID;
    float s = bih0[cc];
    #pragma unroll 8
    for (int k = 0; k < HID; ++k) s += er[k] * wr[k];
    if (g == 0)      tab_rz[(((v << 8) + c) << 1) + 0] = s + bhh0[c];
    else if (g == 1) tab_rz[(((v << 8) + c) << 1) + 1] = s + bhh0[256 + c];
    else             tab_n[(v << 8) + c] = s;
}

// ---- h_init = z @ W_lat.T + b_lat (fp32) ----
__global__ __launch_bounds__(256) void init_h(
    const float* __restrict__ z, const float* __restrict__ Wl, const float* __restrict__ bl,
    float* __restrict__ h0f, float* __restrict__ h1f)
{
    int tid = blockIdx.x * 256 + threadIdx.x;   // b*512 + o
    int b = tid >> 9, o = tid & 511;
    const float* zr = z + b * 32;
    const float* wr = Wl + o * 32;
    float s = bl[o];
    #pragma unroll
    for (int k = 0; k < 32; ++k) s += zr[k] * wr[k];
    if (o < HID) h0f[b * HID + o] = s;
    else         h1f[b * HID + o - HID] = s;
}

// ---- persistent recurrence: 512 blocks x 16 batch rows, 49 steps ----
__global__ __launch_bounds__(512, 2) void gru_persistent(
    const int* __restrict__ toks,
    const float* __restrict__ tab_rz, const float* __restrict__ tab_n,
    const short* __restrict__ Wh0, const short* __restrict__ Wi1, const short* __restrict__ Wh1,
    const float* __restrict__ bhh0, const float* __restrict__ bih1, const float* __restrict__ bhh1,
    const float* __restrict__ h0f, const float* __restrict__ h1f,
    short* __restrict__ Yb)
{
    __shared__ short h0L[16 * HPAD];
    __shared__ short h1L[16 * HPAD];
    __shared__ int tokL[16 * TTOT];

    const int tid = threadIdx.x;
    const int wave = tid >> 6, lane = tid & 63, quad = lane >> 4, l15 = lane & 15;
    const int rowbase = blockIdx.x * 16;

    // --- stage LDS h (bf16) + tokens ---
    {
        int row = tid >> 5, col = (tid & 31) * 8;        // 512 chunks exactly
        const float* s0 = h0f + (size_t)(rowbase + row) * HID + col;
        const float* s1 = h1f + (size_t)(rowbase + row) * HID + col;
        short t0[8], t1[8];
        #pragma unroll
        for (int j = 0; j < 8; ++j) { t0[j] = f2b(s0[j]); t1[j] = f2b(s1[j]); }
        *(bf16x8*)&h0L[row * HPAD + col] = *(bf16x8*)t0;
        *(bf16x8*)&h1L[row * HPAD + col] = *(bf16x8*)t1;
    }
    for (int idx = tid; idx < 16 * TTOT; idx += 512) {
        int row = idx / TTOT, tt = idx - row * TTOT;
        tokL[idx] = (tt == 0) ? START_TOK : toks[(size_t)(rowbase + row) * TTOT + tt];
    }

    // fp32 h carry in registers (C-layout: row quad*4+r, col wave*32+c*16+l15)
    int colc[2]; colc[0] = wave * 32 + l15; colc[1] = colc[0] + 16;
    float h0r[2][4], h1r[2][4];
    #pragma unroll
    for (int c = 0; c < 2; ++c)
        #pragma unroll
        for (int r_ = 0; r_ < 4; ++r_) {
            int row = rowbase + quad * 4 + r_;
            h0r[c][r_] = h0f[(size_t)row * HID + colc[c]];
            h1r[c][r_] = h1f[(size_t)row * HID + colc[c]];
        }

    // hoisted per-thread biases (t-invariant)
    float bn0[2], brr[2], brz[2], bni[2], bnh[2];
    #pragma unroll
    for (int c = 0; c < 2; ++c) {
        int col = colc[c];
        bn0[c] = bhh0[512 + col];
        brr[c] = bih1[col] + bhh1[col];
        brz[c] = bih1[256 + col] + bhh1[256 + col];
        bni[c] = bih1[512 + col];
        bnh[c] = bhh1[512 + col];
    }

    // shared 32-bit weight offsets (same for Wh0/Wh1/Wi1), j = gate*2 + half
    int woff[6];
    #pragma unroll
    for (int g = 0; g < 3; ++g)
        #pragma unroll
        for (int c = 0; c < 2; ++c)
            woff[g * 2 + c] = ((g * 16 + wave * 2 + c) << 12) + lane * 8;

    const int a0base = l15 * HPAD + quad * 8;            // A-frag LDS base (shorts)
    const int hwbase = (quad * 4) * HPAD + colc[0];      // h-write base (shorts)
    int tokrow[4];
    #pragma unroll
    for (int r_ = 0; r_ < 4; ++r_) tokrow[r_] = (quad * 4 + r_) * TTOT;
    short* yptr = Yb + ((((size_t)blockIdx.x << 3) + wave) << 9) + lane * 8;

    __syncthreads();

    for (int t = 0; t < TS; ++t) {
        // ---- merged kloop: gh0 (h0 @ Wh0.T) and gh1 (h1 @ Wh1.T) ----
        f32x4 acc0[6] = {};
        f32x4 accrz[4] = {}, acchn[2] = {};
        #pragma unroll 2
        for (int kc = 0; kc < 8; ++kc) {
            bf16x8 a0 = *(const bf16x8*)&h0L[a0base + kc * 32];
            bf16x8 a1 = *(const bf16x8*)&h1L[a0base + kc * 32];
            #pragma unroll
            for (int j = 0; j < 6; ++j) {
                bf16x8 b0 = *(const bf16x8*)(Wh0 + woff[j] + kc * 512);
                acc0[j] = __builtin_amdgcn_mfma_f32_16x16x32_bf16(a0, b0, acc0[j], 0, 0, 0);
            }
            #pragma unroll
            for (int j = 0; j < 6; ++j) {
                bf16x8 b1 = *(const bf16x8*)(Wh1 + woff[j] + kc * 512);
                if (j < 4) accrz[j] = __builtin_amdgcn_mfma_f32_16x16x32_bf16(a1, b1, accrz[j], 0, 0, 0);
                else       acchn[j - 4] = __builtin_amdgcn_mfma_f32_16x16x32_bf16(a1, b1, acchn[j - 4], 0, 0, 0);
            }
        }
        // ---- layer-0 gates (gi0 from interleaved token table) ----
        #pragma unroll
        for (int r_ = 0; r_ < 4; ++r_) {
            int tok = tokL[tokrow[r_] + t];
            const float2 rz0 = *(const float2*)(tab_rz + (tok << 9) + (colc[0] << 1));
            const float2 rz1 = *(const float2*)(tab_rz + (tok << 9) + (colc[1] << 1));
            float in0 = tab_n[(tok << 8) + colc[0]];
            float in1 = tab_n[(tok << 8) + colc[1]];
            {
                float r = sigm(acc0[0][r_] + rz0.x);
                float z = sigm(acc0[2][r_] + rz0.y);
                float n = tanh_(in0 + r * (acc0[4][r_] + bn0[0]));
                h0r[0][r_] = n + z * (h0r[0][r_] - n);
            }
            {
                float r = sigm(acc0[1][r_] + rz1.x);
                float z = sigm(acc0[3][r_] + rz1.y);
                float n = tanh_(in1 + r * (acc0[5][r_] + bn0[1]));
                h0r[1][r_] = n + z * (h0r[1][r_] - n);
            }
        }
        __syncthreads();   // all waves done reading h0L/h1L
        #pragma unroll
        for (int r_ = 0; r_ < 4; ++r_) {
            unsigned u;
            asm("v_cvt_pk_bf16_f32 %0, %1, %2" : "=v"(u) : "v"(h0r[0][r_]), "v"(h0r[1][r_]));
            int ro = hwbase + r_ * HPAD;
            h0L[ro]      = (short)u;
            h0L[ro + 16] = (short)(u >> 16);
        }
        __syncthreads();   // h0n visible to all

        // ---- kloop gi1 = h0n @ Wi1.T (rz on top of gh1-rz, n separate) ----
        f32x4 accgn[2] = {};
        #pragma unroll 2
        for (int kc = 0; kc < 8; ++kc) {
            bf16x8 a = *(const bf16x8*)&h0L[a0base + kc * 32];
            #pragma unroll
            for (int j = 0; j < 6; ++j) {
                bf16x8 b = *(const bf16x8*)(Wi1 + woff[j] + kc * 512);
                if (j < 4) accrz[j] = __builtin_amdgcn_mfma_f32_16x16x32_bf16(a, b, accrz[j], 0, 0, 0);
                else       accgn[j - 4] = __builtin_amdgcn_mfma_f32_16x16x32_bf16(a, b, accgn[j - 4], 0, 0, 0);
            }
        }
        // ---- layer-1 gates ----
        #pragma unroll
        for (int c = 0; c < 2; ++c)
            #pragma unroll
            for (int r_ = 0; r_ < 4; ++r_) {
                float r = sigm(accrz[c][r_] + brr[c]);
                float z = sigm(accrz[2 + c][r_] + brz[c]);
                float n = tanh_(accgn[c][r_] + bni[c] + r * (acchn[c][r_] + bnh[c]));
                h1r[c][r_] = n + z * (h1r[c][r_] - n);
            }
        #pragma unroll
        for (int r_ = 0; r_ < 4; ++r_) {
            unsigned u;
            asm("v_cvt_pk_bf16_f32 %0, %1, %2" : "=v"(u) : "v"(h1r[0][r_]), "v"(h1r[1][r_]));
            int ro = hwbase + r_ * HPAD;
            h1L[ro]      = (short)u;
            h1L[ro + 16] = (short)(u >> 16);
        }
        __syncthreads();   // h1n visible

        // ---- packed Y[t] write: wave w stores kc=w (one 1KB coalesced store) ----
        *(bf16x8*)yptr = *(const bf16x8*)&h1L[a0base + wave * 32];
        yptr += (size_t)512 * 8 * 512;
        // no extra barrier: next h0L/h1L writes are behind the next barriers
    }
}

// ---- fused head: hdd = relu(Y@W1.T+b1) in LDS, logits = hdd@W2.T+b2 ----
__global__ __launch_bounds__(256) void head_kernel(
    const short* __restrict__ YP, const short* __restrict__ W1P, const float* __restrict__ b1,
    const short* __restrict__ W2P, const float* __restrict__ b2, float* __restrict__ out)
{
    __shared__ short hddL[64 * HPAD];
    int wave = threadIdx.x >> 6;
    int lane = threadIdx.x & 63;
    int quad = lane >> 4;
    int l15  = lane & 15;
    int rbase = blockIdx.x * 64;
    int tt = rbase >> 13;                 // time index (rows = t*8192 + b)
    int mb = (rbase & 8191) >> 4;         // 16-row tile base within t

    { // stage A: hdd tile 64x256; wave w owns n-tiles [w*4, w*4+4)
        const short* ybase = YP + ((size_t)tt * 512 + mb) * 4096 + lane * 8;
        const short* wbase = W1P + (size_t)(wave * 4) * 4096 + lane * 8;
        f32x4 acc[4][4] = {};
        #pragma unroll 2
        for (int kc = 0; kc < 8; ++kc) {
            bf16x8 a[4], bfr[4];
            #pragma unroll
            for (int i = 0; i < 4; ++i) a[i] = *(const bf16x8*)(ybase + (size_t)i * 4096 + kc * 512);
            #pragma unroll
            for (int j = 0; j < 4; ++j) bfr[j] = *(const bf16x8*)(wbase + (size_t)j * 4096 + kc * 512);
            #pragma unroll
            for (int i = 0; i < 4; ++i)
                #pragma unroll
                for (int j = 0; j < 4; ++j)
                    acc[i][j] = __builtin_amdgcn_mfma_f32_16x16x32_bf16(a[i], bfr[j], acc[i][j], 0, 0, 0);
        }
        #pragma unroll
        for (int i = 0; i < 4; ++i)
            #pragma unroll
            for (int j = 0; j < 4; ++j)
                #pragma unroll
                for (int r = 0; r < 4; ++r) {
                    int rl = i * 16 + quad * 4 + r;
                    int c  = wave * 64 + j * 16 + l15;
                    float v = acc[i][j][r] + b1[c];
                    hddL[rl * HPAD + c] = f2b(fmaxf(v, 0.f));
                }
    }
    __syncthreads();
    // stage B: 20 subtiles (10 col-tiles x 2 row-halves) / 4 waves
    for (int s = wave * 5; s < wave * 5 + 5; ++s) {
        int ct = s >> 1, rh = s & 1;
        const short* w2b = W2P + (size_t)ct * 4096 + lane * 8;
        f32x4 acc2[2] = {};
        #pragma unroll 2
        for (int kc = 0; kc < 8; ++kc) {
            bf16x8 bfr = *(const bf16x8*)(w2b + kc * 512);
            #pragma unroll
            for (int it = 0; it < 2; ++it) {
                bf16x8 a = *(const bf16x8*)&hddL[(rh * 32 + it * 16 + l15) * HPAD + kc * 32 + quad * 8];
                acc2[it] = __builtin_amdgcn_mfma_f32_16x16x32_bf16(a, bfr, acc2[it], 0, 0, 0);
            }
        }
        int col = ct * 16 + l15;
        if (col < VOCAB) {
            #pragma unroll
            for (int it = 0; it < 2; ++it)
                #pragma unroll
                for (int r = 0; r < 4; ++r) {
                    int rl = rh * 32 + it * 16 + quad * 4 + r;
                    int gr = rbase + rl;
                    int t2 = gr >> 13;
                    int bb = gr & 8191;
                    out[((size_t)bb * TS + t2) * VOCAB + col] = acc2[it][r] + b2[col];
                }
        }
    }
}

// ---- generated = target_tokens[:,1:] as float ----
__global__ __launch_bounds__(256) void gen_copy(const int* __restrict__ toks, float* __restrict__ out2)
{
    int tid = blockIdx.x * 256 + threadIdx.x;
    if (tid < BATCH * TS) {
        int b = tid / TS, j = tid - b * TS;
        out2[tid] = (float)toks[b * TTOT + j + 1];
    }
}

extern "C" void kernel_launch(void* const* d_in, const int* in_sizes, int n_in,
                              void* d_out, int out_size, void* d_ws, size_t ws_size,
                              hipStream_t stream) {
    const float* z     = (const float*)d_in[0];
    const int*   toks  = (const int*)d_in[1];
    const float* emb   = (const float*)d_in[2];
    const float* W_lat = (const float*)d_in[3];
    const float* b_lat = (const float*)d_in[4];
    const float* W_ih0 = (const float*)d_in[5];
    const float* W_hh0 = (const float*)d_in[6];
    const float* b_ih0 = (const float*)d_in[7];
    const float* b_hh0 = (const float*)d_in[8];
    const float* W_ih1 = (const float*)d_in[9];
    const float* W_hh1 = (const float*)d_in[10];
    const float* b_ih1 = (const float*)d_in[11];
    const float* b_hh1 = (const float*)d_in[12];
    const float* W1    = (const float*)d_in[13];
    const float* b1    = (const float*)d_in[14];
    const float* W2    = (const float*)d_in[15];
    const float* b2    = (const float*)d_in[16];

    char* w = (char*)d_ws;
    short* Yb    = (short*)(w + OFF_Y);
    short* Wh0b  = (short*)(w + OFF_WH0B);
    short* Wi1b  = (short*)(w + OFF_WI1B);
    short* Wh1b  = (short*)(w + OFF_WH1B);
    short* W1b   = (short*)(w + OFF_W1B);
    short* W2b   = (short*)(w + OFF_W2B);
    float* tabrz = (float*)(w + OFF_TAB);
    float* tabn  = (float*)(w + OFF_TABN);
    float* h0f   = (float*)(w + OFF_H0F);
    float* h1f   = (float*)(w + OFF_H1F);

    float* out_logits = (float*)d_out;
    float* out_gen    = out_logits + (size_t)BATCH * TS * VOCAB;

    convert_w<<<2720, 256, 0, stream>>>(W_hh0, W_ih1, W_hh1, W1, W2,
                                        Wh0b, Wi1b, Wh1b, W1b, W2b);
    build_tab2<<<(VOCAB * N3 + 255) / 256, 256, 0, stream>>>(emb, W_ih0, b_ih0, b_hh0, tabrz, tabn);
    init_h<<<(BATCH * 512) / 256, 256, 0, stream>>>(z, W_lat, b_lat, h0f, h1f);
    gen_copy<<<(BATCH * TS + 255) / 256, 256, 0, stream>>>(toks, out_gen);

    gru_persistent<<<512, 512, 0, stream>>>(toks, tabrz, tabn, Wh0b, Wi1b, Wh1b,
                                            b_hh0, b_ih1, b_hh1, h0f, h1f, Yb);

    head_kernel<<<(BATCH * TS) / 64, 256, 0, stream>>>(Yb, W1b, b1, W2b, b2, out_logits);
}

// Round 4
// 1722.540 us; speedup vs baseline: 1.5073x; 1.2303x over previous
//
#include <hip/hip_runtime.h>
#include <hip/hip_bf16.h>
#include <math.h>

// Round 6: resubmit of Round 5 (infra failure, no result).
//  - split kloop: gh0-only pass (acc live 24) -> gates0 -> gh1+gi1 merged pass
//    (acc live 32); peak unified regs ~100 <= 128.
//  - amdgpu_waves_per_eu(4): caps unified VGPR+AGPR at 512/4=128 (the
//    __launch_bounds__(512,4) form empirically capped at 64 -> spill disaster).
//  - double-buffered h0L/h1L: 2 barriers/step instead of 3.

#define BATCH 8192
#define TTOT 50
#define TS 49
#define HID 256
#define N3 768
#define VOCAB 148
#define START_TOK 1
#define HPAD 264

typedef short bf16x8 __attribute__((ext_vector_type(8)));
typedef float f32x4 __attribute__((ext_vector_type(4)));

// ---- workspace layout (bytes) ----
constexpr size_t OFF_Y    = 0;                        // 49*8192*256*2 (packed)
constexpr size_t OFF_WH0B = OFF_Y + 205520896;        // 768*256*2 packed
constexpr size_t OFF_WI1B = OFF_WH0B + 393216;
constexpr size_t OFF_WH1B = OFF_WI1B + 393216;
constexpr size_t OFF_W1B  = OFF_WH1B + 393216;        // 256*256*2 packed
constexpr size_t OFF_W2B  = OFF_W1B + 131072;         // 160*256*2 packed (rows >=148 zero)
constexpr size_t OFF_TAB  = OFF_W2B + 81920;          // tab_rz 148*256*2*4 = 303104
constexpr size_t OFF_TABN = OFF_TAB + 303104;         // tab_n  148*256*4   = 151552
constexpr size_t OFF_H0F  = OFF_TAB + 454656;         // 8192*256*4
constexpr size_t OFF_H1F  = OFF_H0F + 8388608;

__device__ __forceinline__ short f2b(float f) {
    union { float f; unsigned int u; } v; v.f = f;
    unsigned int u = v.u;
    return (short)((u + 0x7FFFu + ((u >> 16) & 1u)) >> 16);
}
__device__ __forceinline__ float sigm(float x) {
    return 1.f / (1.f + __expf(-x));
}
__device__ __forceinline__ float tanh_(float x) {
    x = fmaxf(x, -15.f);
    float e = __expf(-2.f * x);
    return (1.f - e) / (1.f + e);
}

// ---- convert + swizzle weights into fragment order P[nt][kc][lane][8] ----
__global__ __launch_bounds__(256) void convert_w(
    const float* __restrict__ Wh0, const float* __restrict__ Wi1, const float* __restrict__ Wh1,
    const float* __restrict__ W1, const float* __restrict__ W2,
    short* __restrict__ Wh0b, short* __restrict__ Wi1b, short* __restrict__ Wh1b,
    short* __restrict__ W1b, short* __restrict__ W2b)
{
    int tid = blockIdx.x * 256 + threadIdx.x;
    const int WSZ = N3 * HID; // 196608
    const float* S; short* D; int n; bool pad148 = false;
    if (tid < WSZ) { S = Wh0; D = Wh0b; n = tid; }
    else if (tid < 2 * WSZ) { S = Wi1; D = Wi1b; n = tid - WSZ; }
    else if (tid < 3 * WSZ) { S = Wh1; D = Wh1b; n = tid - 2 * WSZ; }
    else if (tid < 3 * WSZ + 65536) { S = W1; D = W1b; n = tid - 3 * WSZ; }
    else if (tid < 3 * WSZ + 65536 + 40960) { S = W2; D = W2b; n = tid - 3 * WSZ - 65536; pad148 = true; }
    else return;
    int e = n & 7, lane = (n >> 3) & 63, kc = (n >> 9) & 7, nt = n >> 12;
    int row = nt * 16 + (lane & 15);
    int k = kc * 32 + (lane >> 4) * 8 + e;
    float v = (pad148 && row >= VOCAB) ? 0.f : S[row * HID + k];
    D[n] = f2b(v);
}

// ---- token table, interleaved ----
__global__ __launch_bounds__(256) void build_tab2(
    const float* __restrict__ emb, const float* __restrict__ Wih0,
    const float* __restrict__ bih0, const float* __restrict__ bhh0,
    float* __restrict__ tab_rz, float* __restrict__ tab_n)
{
    int o = blockIdx.x * 256 + threadIdx.x;
    if (o >= VOCAB * N3) return;
    int v = o / N3, cc = o - v * N3;
    int g = cc >> 8, c = cc & 255;
    const float* er = emb + v * HID;
    const float* wr = Wih0 + cc * HID;
    float s = bih0[cc];
    #pragma unroll 8
    for (int k = 0; k < HID; ++k) s += er[k] * wr[k];
    if (g == 0)      tab_rz[(((v << 8) + c) << 1) + 0] = s + bhh0[c];
    else if (g == 1) tab_rz[(((v << 8) + c) << 1) + 1] = s + bhh0[256 + c];
    else             tab_n[(v << 8) + c] = s;
}

// ---- h_init = z @ W_lat.T + b_lat (fp32) ----
__global__ __launch_bounds__(256) void init_h(
    const float* __restrict__ z, const float* __restrict__ Wl, const float* __restrict__ bl,
    float* __restrict__ h0f, float* __restrict__ h1f)
{
    int tid = blockIdx.x * 256 + threadIdx.x;   // b*512 + o
    int b = tid >> 9, o = tid & 511;
    const float* zr = z + b * 32;
    const float* wr = Wl + o * 32;
    float s = bl[o];
    #pragma unroll
    for (int k = 0; k < 32; ++k) s += zr[k] * wr[k];
    if (o < HID) h0f[b * HID + o] = s;
    else         h1f[b * HID + o - HID] = s;
}

// ---- persistent recurrence: 512 blocks x 16 batch rows, 49 steps ----
__global__ __launch_bounds__(512) __attribute__((amdgpu_waves_per_eu(4)))
void gru_persistent(
    const int* __restrict__ toks,
    const float* __restrict__ tab_rz, const float* __restrict__ tab_n,
    const short* __restrict__ Wh0, const short* __restrict__ Wi1, const short* __restrict__ Wh1,
    const float* __restrict__ bhh0, const float* __restrict__ bih1, const float* __restrict__ bhh1,
    const float* __restrict__ h0f, const float* __restrict__ h1f,
    short* __restrict__ Yb)
{
    __shared__ short h0L[2][16 * HPAD];
    __shared__ short h1L[2][16 * HPAD];
    __shared__ int tokL[16 * TTOT];

    const int tid = threadIdx.x;
    const int wave = tid >> 6, lane = tid & 63, quad = lane >> 4, l15 = lane & 15;
    const int rowbase = blockIdx.x * 16;

    // --- stage LDS h (bf16, buffer 0) + tokens ---
    {
        int row = tid >> 5, col = (tid & 31) * 8;        // 512 chunks exactly
        const float* s0 = h0f + (size_t)(rowbase + row) * HID + col;
        const float* s1 = h1f + (size_t)(rowbase + row) * HID + col;
        short t0[8], t1[8];
        #pragma unroll
        for (int j = 0; j < 8; ++j) { t0[j] = f2b(s0[j]); t1[j] = f2b(s1[j]); }
        *(bf16x8*)&h0L[0][row * HPAD + col] = *(bf16x8*)t0;
        *(bf16x8*)&h1L[0][row * HPAD + col] = *(bf16x8*)t1;
    }
    for (int idx = tid; idx < 16 * TTOT; idx += 512) {
        int row = idx / TTOT, tt = idx - row * TTOT;
        tokL[idx] = (tt == 0) ? START_TOK : toks[(size_t)(rowbase + row) * TTOT + tt];
    }

    // fp32 h carry in registers (C-layout: row quad*4+r, col wave*32+c*16+l15)
    int colc[2]; colc[0] = wave * 32 + l15; colc[1] = colc[0] + 16;
    float h0r[2][4], h1r[2][4];
    #pragma unroll
    for (int c = 0; c < 2; ++c)
        #pragma unroll
        for (int r_ = 0; r_ < 4; ++r_) {
            int row = rowbase + quad * 4 + r_;
            h0r[c][r_] = h0f[(size_t)row * HID + colc[c]];
            h1r[c][r_] = h1f[(size_t)row * HID + colc[c]];
        }

    // hoisted per-thread biases (t-invariant)
    float bn0[2], brr[2], brz[2], bni[2], bnh[2];
    #pragma unroll
    for (int c = 0; c < 2; ++c) {
        int col = colc[c];
        bn0[c] = bhh0[512 + col];
        brr[c] = bih1[col] + bhh1[col];
        brz[c] = bih1[256 + col] + bhh1[256 + col];
        bni[c] = bih1[512 + col];
        bnh[c] = bhh1[512 + col];
    }

    // shared 32-bit weight offsets (same for Wh0/Wh1/Wi1), j = gate*2 + half
    int woff[6];
    #pragma unroll
    for (int g = 0; g < 3; ++g)
        #pragma unroll
        for (int c = 0; c < 2; ++c)
            woff[g * 2 + c] = ((g * 16 + wave * 2 + c) << 12) + lane * 8;

    const int a0base = l15 * HPAD + quad * 8;            // A-frag LDS base (shorts)
    const int hwbase = (quad * 4) * HPAD + colc[0];      // h-write base (shorts)
    int tokrow[4];
    #pragma unroll
    for (int r_ = 0; r_ < 4; ++r_) tokrow[r_] = (quad * 4 + r_) * TTOT;
    short* yptr = Yb + ((((size_t)blockIdx.x << 3) + wave) << 9) + lane * 8;

    int rb = 0, wb = 1;
    __syncthreads();

    for (int t = 0; t < TS; ++t) {
        // ---- kloop A: gh0 = h0 @ Wh0.T only (24 acc regs live) ----
        f32x4 acc0[6] = {};
        #pragma unroll 1
        for (int kc = 0; kc < 8; ++kc) {
            bf16x8 a0 = *(const bf16x8*)&h0L[rb][a0base + kc * 32];
            #pragma unroll
            for (int j = 0; j < 6; ++j) {
                bf16x8 b0 = *(const bf16x8*)(Wh0 + woff[j] + kc * 512);
                acc0[j] = __builtin_amdgcn_mfma_f32_16x16x32_bf16(a0, b0, acc0[j], 0, 0, 0);
            }
        }
        // ---- layer-0 gates (gi0 from interleaved token table) ----
        #pragma unroll
        for (int r_ = 0; r_ < 4; ++r_) {
            int tok = tokL[tokrow[r_] + t];
            const float2 rz0 = *(const float2*)(tab_rz + (tok << 9) + (colc[0] << 1));
            const float2 rz1 = *(const float2*)(tab_rz + (tok << 9) + (colc[1] << 1));
            float in0 = tab_n[(tok << 8) + colc[0]];
            float in1 = tab_n[(tok << 8) + colc[1]];
            {
                float r = sigm(acc0[0][r_] + rz0.x);
                float z = sigm(acc0[2][r_] + rz0.y);
                float n = tanh_(in0 + r * (acc0[4][r_] + bn0[0]));
                h0r[0][r_] = n + z * (h0r[0][r_] - n);
            }
            {
                float r = sigm(acc0[1][r_] + rz1.x);
                float z = sigm(acc0[3][r_] + rz1.y);
                float n = tanh_(in1 + r * (acc0[5][r_] + bn0[1]));
                h0r[1][r_] = n + z * (h0r[1][r_] - n);
            }
        }
        // write h0n to the ALTERNATE buffer (no reader conflict -> no pre-barrier)
        #pragma unroll
        for (int r_ = 0; r_ < 4; ++r_) {
            unsigned u;
            asm("v_cvt_pk_bf16_f32 %0, %1, %2" : "=v"(u) : "v"(h0r[0][r_]), "v"(h0r[1][r_]));
            int ro = hwbase + r_ * HPAD;
            h0L[wb][ro]      = (short)u;
            h0L[wb][ro + 16] = (short)(u >> 16);
        }
        __syncthreads();   // B1: h0n visible; everyone past kloop-A reads

        // ---- kloop B: gh1 = h1 @ Wh1.T  +  gi1 = h0n @ Wi1.T (32 acc regs) ----
        f32x4 accrz[4] = {}, acchn[2] = {}, accgn[2] = {};
        #pragma unroll 1
        for (int kc = 0; kc < 8; ++kc) {
            bf16x8 a1 = *(const bf16x8*)&h1L[rb][a0base + kc * 32];
            bf16x8 an = *(const bf16x8*)&h0L[wb][a0base + kc * 32];
            #pragma unroll
            for (int j = 0; j < 6; ++j) {
                bf16x8 b1 = *(const bf16x8*)(Wh1 + woff[j] + kc * 512);
                if (j < 4) accrz[j] = __builtin_amdgcn_mfma_f32_16x16x32_bf16(a1, b1, accrz[j], 0, 0, 0);
                else       acchn[j - 4] = __builtin_amdgcn_mfma_f32_16x16x32_bf16(a1, b1, acchn[j - 4], 0, 0, 0);
            }
            #pragma unroll
            for (int j = 0; j < 6; ++j) {
                bf16x8 b = *(const bf16x8*)(Wi1 + woff[j] + kc * 512);
                if (j < 4) accrz[j] = __builtin_amdgcn_mfma_f32_16x16x32_bf16(an, b, accrz[j], 0, 0, 0);
                else       accgn[j - 4] = __builtin_amdgcn_mfma_f32_16x16x32_bf16(an, b, accgn[j - 4], 0, 0, 0);
            }
        }
        // ---- layer-1 gates ----
        #pragma unroll
        for (int c = 0; c < 2; ++c)
            #pragma unroll
            for (int r_ = 0; r_ < 4; ++r_) {
                float r = sigm(accrz[c][r_] + brr[c]);
                float z = sigm(accrz[2 + c][r_] + brz[c]);
                float n = tanh_(accgn[c][r_] + bni[c] + r * (acchn[c][r_] + bnh[c]));
                h1r[c][r_] = n + z * (h1r[c][r_] - n);
            }
        #pragma unroll
        for (int r_ = 0; r_ < 4; ++r_) {
            unsigned u;
            asm("v_cvt_pk_bf16_f32 %0, %1, %2" : "=v"(u) : "v"(h1r[0][r_]), "v"(h1r[1][r_]));
            int ro = hwbase + r_ * HPAD;
            h1L[wb][ro]      = (short)u;
            h1L[wb][ro + 16] = (short)(u >> 16);
        }
        __syncthreads();   // B2: h1n visible

        // ---- packed Y[t] write: wave w stores kc=w (one 1KB coalesced store) ----
        *(bf16x8*)yptr = *(const bf16x8*)&h1L[wb][a0base + wave * 32];
        yptr += (size_t)512 * 8 * 512;

        rb ^= 1; wb ^= 1;
    }
}

// ---- fused head: hdd = relu(Y@W1.T+b1) in LDS, logits = hdd@W2.T+b2 ----
__global__ __launch_bounds__(256) void head_kernel(
    const short* __restrict__ YP, const short* __restrict__ W1P, const float* __restrict__ b1,
    const short* __restrict__ W2P, const float* __restrict__ b2, float* __restrict__ out)
{
    __shared__ short hddL[64 * HPAD];
    int wave = threadIdx.x >> 6;
    int lane = threadIdx.x & 63;
    int quad = lane >> 4;
    int l15  = lane & 15;
    int rbase = blockIdx.x * 64;
    int tt = rbase >> 13;                 // time index (rows = t*8192 + b)
    int mb = (rbase & 8191) >> 4;         // 16-row tile base within t

    { // stage A: hdd tile 64x256; wave w owns n-tiles [w*4, w*4+4)
        const short* ybase = YP + ((size_t)tt * 512 + mb) * 4096 + lane * 8;
        const short* wbase = W1P + (size_t)(wave * 4) * 4096 + lane * 8;
        f32x4 acc[4][4] = {};
        #pragma unroll 2
        for (int kc = 0; kc < 8; ++kc) {
            bf16x8 a[4], bfr[4];
            #pragma unroll
            for (int i = 0; i < 4; ++i) a[i] = *(const bf16x8*)(ybase + (size_t)i * 4096 + kc * 512);
            #pragma unroll
            for (int j = 0; j < 4; ++j) bfr[j] = *(const bf16x8*)(wbase + (size_t)j * 4096 + kc * 512);
            #pragma unroll
            for (int i = 0; i < 4; ++i)
                #pragma unroll
                for (int j = 0; j < 4; ++j)
                    acc[i][j] = __builtin_amdgcn_mfma_f32_16x16x32_bf16(a[i], bfr[j], acc[i][j], 0, 0, 0);
        }
        #pragma unroll
        for (int i = 0; i < 4; ++i)
            #pragma unroll
            for (int j = 0; j < 4; ++j)
                #pragma unroll
                for (int r = 0; r < 4; ++r) {
                    int rl = i * 16 + quad * 4 + r;
                    int c  = wave * 64 + j * 16 + l15;
                    float v = acc[i][j][r] + b1[c];
                    hddL[rl * HPAD + c] = f2b(fmaxf(v, 0.f));
                }
    }
    __syncthreads();
    // stage B: 20 subtiles (10 col-tiles x 2 row-halves) / 4 waves
    for (int s = wave * 5; s < wave * 5 + 5; ++s) {
        int ct = s >> 1, rh = s & 1;
        const short* w2b = W2P + (size_t)ct * 4096 + lane * 8;
        f32x4 acc2[2] = {};
        #pragma unroll 2
        for (int kc = 0; kc < 8; ++kc) {
            bf16x8 bfr = *(const bf16x8*)(w2b + kc * 512);
            #pragma unroll
            for (int it = 0; it < 2; ++it) {
                bf16x8 a = *(const bf16x8*)&hddL[(rh * 32 + it * 16 + l15) * HPAD + kc * 32 + quad * 8];
                acc2[it] = __builtin_amdgcn_mfma_f32_16x16x32_bf16(a, bfr, acc2[it], 0, 0, 0);
            }
        }
        int col = ct * 16 + l15;
        if (col < VOCAB) {
            #pragma unroll
            for (int it = 0; it < 2; ++it)
                #pragma unroll
                for (int r = 0; r < 4; ++r) {
                    int rl = rh * 32 + it * 16 + quad * 4 + r;
                    int gr = rbase + rl;
                    int t2 = gr >> 13;
                    int bb = gr & 8191;
                    out[((size_t)bb * TS + t2) * VOCAB + col] = acc2[it][r] + b2[col];
                }
        }
    }
}

// ---- generated = target_tokens[:,1:] as float ----
__global__ __launch_bounds__(256) void gen_copy(const int* __restrict__ toks, float* __restrict__ out2)
{
    int tid = blockIdx.x * 256 + threadIdx.x;
    if (tid < BATCH * TS) {
        int b = tid / TS, j = tid - b * TS;
        out2[tid] = (float)toks[b * TTOT + j + 1];
    }
}

extern "C" void kernel_launch(void* const* d_in, const int* in_sizes, int n_in,
                              void* d_out, int out_size, void* d_ws, size_t ws_size,
                              hipStream_t stream) {
    const float* z     = (const float*)d_in[0];
    const int*   toks  = (const int*)d_in[1];
    const float* emb   = (const float*)d_in[2];
    const float* W_lat = (const float*)d_in[3];
    const float* b_lat = (const float*)d_in[4];
    const float* W_ih0 = (const float*)d_in[5];
    const float* W_hh0 = (const float*)d_in[6];
    const float* b_ih0 = (const float*)d_in[7];
    const float* b_hh0 = (const float*)d_in[8];
    const float* W_ih1 = (const float*)d_in[9];
    const float* W_hh1 = (const float*)d_in[10];
    const float* b_ih1 = (const float*)d_in[11];
    const float* b_hh1 = (const float*)d_in[12];
    const float* W1    = (const float*)d_in[13];
    const float* b1    = (const float*)d_in[14];
    const float* W2    = (const float*)d_in[15];
    const float* b2    = (const float*)d_in[16];

    char* w = (char*)d_ws;
    short* Yb    = (short*)(w + OFF_Y);
    short* Wh0b  = (short*)(w + OFF_WH0B);
    short* Wi1b  = (short*)(w + OFF_WI1B);
    short* Wh1b  = (short*)(w + OFF_WH1B);
    short* W1b   = (short*)(w + OFF_W1B);
    short* W2b   = (short*)(w + OFF_W2B);
    float* tabrz = (float*)(w + OFF_TAB);
    float* tabn  = (float*)(w + OFF_TABN);
    float* h0f   = (float*)(w + OFF_H0F);
    float* h1f   = (float*)(w + OFF_H1F);

    float* out_logits = (float*)d_out;
    float* out_gen    = out_logits + (size_t)BATCH * TS * VOCAB;

    convert_w<<<2720, 256, 0, stream>>>(W_hh0, W_ih1, W_hh1, W1, W2,
                                        Wh0b, Wi1b, Wh1b, W1b, W2b);
    build_tab2<<<(VOCAB * N3 + 255) / 256, 256, 0, stream>>>(emb, W_ih0, b_ih0, b_hh0, tabrz, tabn);
    init_h<<<(BATCH * 512) / 256, 256, 0, stream>>>(z, W_lat, b_lat, h0f, h1f);
    gen_copy<<<(BATCH * TS + 255) / 256, 256, 0, stream>>>(toks, out_gen);

    gru_persistent<<<512, 512, 0, stream>>>(toks, tabrz, tabn, Wh0b, Wi1b, Wh1b,
                                            b_hh0, b_ih1, b_hh1, h0f, h1f, Yb);

    head_kernel<<<(BATCH * TS) / 64, 256, 0, stream>>>(Yb, W1b, b1, W2b, b2, out_logits);
}

// Round 5
// 1403.900 us; speedup vs baseline: 1.8494x; 1.2270x over previous
//
#include <hip/hip_runtime.h>
#include <hip/hip_bf16.h>
#include <math.h>

// Round 7: cut L2 weight traffic 2x. Analysis: each block re-streams all three
// 768x256 bf16 weights per step; R6 = 512 blocks -> 29.6 GB L2 traffic -> 858us
// floor (measured 1295 at 66% of L2 peak). Now 256 blocks x 32 rows x 1024 thr
// (16 waves, 1 n-tile/gate/wave): traffic halves to 14.8 GB (429us floor) at
// the same 4 waves/SIMD occupancy and SMALLER per-wave acc footprint.

#define BATCH 8192
#define TTOT 50
#define TS 49
#define HID 256
#define N3 768
#define VOCAB 148
#define START_TOK 1
#define HPAD 264

typedef short bf16x8 __attribute__((ext_vector_type(8)));
typedef float f32x4 __attribute__((ext_vector_type(4)));

// ---- workspace layout (bytes) ----
constexpr size_t OFF_Y    = 0;                        // 49*8192*256*2 (packed)
constexpr size_t OFF_WH0B = OFF_Y + 205520896;        // 768*256*2 packed
constexpr size_t OFF_WI1B = OFF_WH0B + 393216;
constexpr size_t OFF_WH1B = OFF_WI1B + 393216;
constexpr size_t OFF_W1B  = OFF_WH1B + 393216;        // 256*256*2 packed
constexpr size_t OFF_W2B  = OFF_W1B + 131072;         // 160*256*2 packed (rows >=148 zero)
constexpr size_t OFF_TAB  = OFF_W2B + 81920;          // tab_rz 148*256*2*4 = 303104
constexpr size_t OFF_TABN = OFF_TAB + 303104;         // tab_n  148*256*4   = 151552
constexpr size_t OFF_H0F  = OFF_TAB + 454656;         // 8192*256*4
constexpr size_t OFF_H1F  = OFF_H0F + 8388608;

__device__ __forceinline__ short f2b(float f) {
    union { float f; unsigned int u; } v; v.f = f;
    unsigned int u = v.u;
    return (short)((u + 0x7FFFu + ((u >> 16) & 1u)) >> 16);
}
__device__ __forceinline__ float sigm(float x) {
    return 1.f / (1.f + __expf(-x));
}
__device__ __forceinline__ float tanh_(float x) {
    x = fmaxf(x, -15.f);
    float e = __expf(-2.f * x);
    return (1.f - e) / (1.f + e);
}

// ---- convert + swizzle weights into fragment order P[nt][kc][lane][8] ----
__global__ __launch_bounds__(256) void convert_w(
    const float* __restrict__ Wh0, const float* __restrict__ Wi1, const float* __restrict__ Wh1,
    const float* __restrict__ W1, const float* __restrict__ W2,
    short* __restrict__ Wh0b, short* __restrict__ Wi1b, short* __restrict__ Wh1b,
    short* __restrict__ W1b, short* __restrict__ W2b)
{
    int tid = blockIdx.x * 256 + threadIdx.x;
    const int WSZ = N3 * HID; // 196608
    const float* S; short* D; int n; bool pad148 = false;
    if (tid < WSZ) { S = Wh0; D = Wh0b; n = tid; }
    else if (tid < 2 * WSZ) { S = Wi1; D = Wi1b; n = tid - WSZ; }
    else if (tid < 3 * WSZ) { S = Wh1; D = Wh1b; n = tid - 2 * WSZ; }
    else if (tid < 3 * WSZ + 65536) { S = W1; D = W1b; n = tid - 3 * WSZ; }
    else if (tid < 3 * WSZ + 65536 + 40960) { S = W2; D = W2b; n = tid - 3 * WSZ - 65536; pad148 = true; }
    else return;
    int e = n & 7, lane = (n >> 3) & 63, kc = (n >> 9) & 7, nt = n >> 12;
    int row = nt * 16 + (lane & 15);
    int k = kc * 32 + (lane >> 4) * 8 + e;
    float v = (pad148 && row >= VOCAB) ? 0.f : S[row * HID + k];
    D[n] = f2b(v);
}

// ---- token table, interleaved ----
__global__ __launch_bounds__(256) void build_tab2(
    const float* __restrict__ emb, const float* __restrict__ Wih0,
    const float* __restrict__ bih0, const float* __restrict__ bhh0,
    float* __restrict__ tab_rz, float* __restrict__ tab_n)
{
    int o = blockIdx.x * 256 + threadIdx.x;
    if (o >= VOCAB * N3) return;
    int v = o / N3, cc = o - v * N3;
    int g = cc >> 8, c = cc & 255;
    const float* er = emb + v * HID;
    const float* wr = Wih0 + cc * HID;
    float s = bih0[cc];
    #pragma unroll 8
    for (int k = 0; k < HID; ++k) s += er[k] * wr[k];
    if (g == 0)      tab_rz[(((v << 8) + c) << 1) + 0] = s + bhh0[c];
    else if (g == 1) tab_rz[(((v << 8) + c) << 1) + 1] = s + bhh0[256 + c];
    else             tab_n[(v << 8) + c] = s;
}

// ---- h_init = z @ W_lat.T + b_lat (fp32) ----
__global__ __launch_bounds__(256) void init_h(
    const float* __restrict__ z, const float* __restrict__ Wl, const float* __restrict__ bl,
    float* __restrict__ h0f, float* __restrict__ h1f)
{
    int tid = blockIdx.x * 256 + threadIdx.x;   // b*512 + o
    int b = tid >> 9, o = tid & 511;
    const float* zr = z + b * 32;
    const float* wr = Wl + o * 32;
    float s = bl[o];
    #pragma unroll
    for (int k = 0; k < 32; ++k) s += zr[k] * wr[k];
    if (o < HID) h0f[b * HID + o] = s;
    else         h1f[b * HID + o - HID] = s;
}

// ---- persistent recurrence: 256 blocks x 32 batch rows x 1024 threads ----
// wave w (0..15) owns n-tile (g*16 + w) of each gate g; M-tiles i=0,1.
__global__ __launch_bounds__(1024) __attribute__((amdgpu_waves_per_eu(4)))
void gru_persistent(
    const int* __restrict__ toks,
    const float* __restrict__ tab_rz, const float* __restrict__ tab_n,
    const short* __restrict__ Wh0, const short* __restrict__ Wi1, const short* __restrict__ Wh1,
    const float* __restrict__ bhh0, const float* __restrict__ bih1, const float* __restrict__ bhh1,
    const float* __restrict__ h0f, const float* __restrict__ h1f,
    short* __restrict__ Yb)
{
    __shared__ short h0L[2][32 * HPAD];
    __shared__ short h1L[2][32 * HPAD];
    __shared__ int tokL[32 * TTOT];

    const int tid = threadIdx.x;
    const int wave = tid >> 6, lane = tid & 63, quad = lane >> 4, l15 = lane & 15;
    const int rowbase = blockIdx.x * 32;

    // --- stage LDS h (bf16, buffer 0) + tokens ---
    {
        int row = tid >> 5, col = (tid & 31) * 8;        // 1024 = 32 rows x 32 chunks
        const float* s0 = h0f + (size_t)(rowbase + row) * HID + col;
        const float* s1 = h1f + (size_t)(rowbase + row) * HID + col;
        short t0[8], t1[8];
        #pragma unroll
        for (int j = 0; j < 8; ++j) { t0[j] = f2b(s0[j]); t1[j] = f2b(s1[j]); }
        *(bf16x8*)&h0L[0][row * HPAD + col] = *(bf16x8*)t0;
        *(bf16x8*)&h1L[0][row * HPAD + col] = *(bf16x8*)t1;
    }
    for (int idx = tid; idx < 32 * TTOT; idx += 1024) {
        int row = idx / TTOT, tt = idx - row * TTOT;
        tokL[idx] = (tt == 0) ? START_TOK : toks[(size_t)(rowbase + row) * TTOT + tt];
    }

    // fp32 h carry: thread owns col=wave*16+l15, rows 16i+quad*4+r
    const int colc = wave * 16 + l15;
    float h0r[2][4], h1r[2][4];
    #pragma unroll
    for (int i = 0; i < 2; ++i)
        #pragma unroll
        for (int r_ = 0; r_ < 4; ++r_) {
            int row = rowbase + 16 * i + quad * 4 + r_;
            h0r[i][r_] = h0f[(size_t)row * HID + colc];
            h1r[i][r_] = h1f[(size_t)row * HID + colc];
        }

    // hoisted per-thread biases (t-invariant)
    const float bn0 = bhh0[512 + colc];
    const float brr = bih1[colc] + bhh1[colc];
    const float brz = bih1[256 + colc] + bhh1[256 + colc];
    const float bni = bih1[512 + colc];
    const float bnh = bhh1[512 + colc];

    // 32-bit weight offsets (shared across Wh0/Wh1/Wi1): nt = g*16 + wave
    int woff[3];
    #pragma unroll
    for (int g = 0; g < 3; ++g)
        woff[g] = ((g * 16 + wave) << 12) + lane * 8;

    const int abase0 = l15 * HPAD + quad * 8;            // A-frag LDS base, M-tile 0
    const int abase1 = (16 + l15) * HPAD + quad * 8;     // M-tile 1
    const int hwbase = (quad * 4) * HPAD + colc;         // h-write base (shorts)
    const int ybase  = ((wave >> 3) * 16 + l15) * HPAD + (wave & 7) * 32 + quad * 8;
    short* yptr = Yb + ((((size_t)(blockIdx.x * 2 + (wave >> 3))) * 8 + (wave & 7)) << 9) + lane * 8;

    int rb = 0, wb = 1;
    __syncthreads();

    for (int t = 0; t < TS; ++t) {
        // ---- kloop A: gh0 = h0 @ Wh0.T (acc 24 regs) ----
        f32x4 acc0[2][3] = {};
        #pragma unroll 1
        for (int kc = 0; kc < 8; ++kc) {
            bf16x8 a0[2];
            a0[0] = *(const bf16x8*)&h0L[rb][abase0 + kc * 32];
            a0[1] = *(const bf16x8*)&h0L[rb][abase1 + kc * 32];
            #pragma unroll
            for (int g = 0; g < 3; ++g) {
                bf16x8 b = *(const bf16x8*)(Wh0 + woff[g] + kc * 512);
                #pragma unroll
                for (int i = 0; i < 2; ++i)
                    acc0[i][g] = __builtin_amdgcn_mfma_f32_16x16x32_bf16(a0[i], b, acc0[i][g], 0, 0, 0);
            }
        }
        // ---- layer-0 gates ----
        #pragma unroll
        for (int i = 0; i < 2; ++i)
            #pragma unroll
            for (int r_ = 0; r_ < 4; ++r_) {
                int tok = tokL[(16 * i + quad * 4 + r_) * TTOT + t];
                const float2 rz = *(const float2*)(tab_rz + (tok << 9) + (colc << 1));
                float inn = tab_n[(tok << 8) + colc];
                float r = sigm(acc0[i][0][r_] + rz.x);
                float z = sigm(acc0[i][1][r_] + rz.y);
                float n = tanh_(inn + r * (acc0[i][2][r_] + bn0));
                h0r[i][r_] = n + z * (h0r[i][r_] - n);
            }
        // write h0n to ALTERNATE buffer (pack M-tile pair with cvt_pk)
        #pragma unroll
        for (int r_ = 0; r_ < 4; ++r_) {
            unsigned u;
            asm("v_cvt_pk_bf16_f32 %0, %1, %2" : "=v"(u) : "v"(h0r[0][r_]), "v"(h0r[1][r_]));
            int ro = hwbase + r_ * HPAD;
            h0L[wb][ro]             = (short)u;
            h0L[wb][ro + 16 * HPAD] = (short)(u >> 16);
        }
        __syncthreads();   // B1: h0n visible

        // ---- kloop B: gh1 = h1 @ Wh1.T + gi1 = h0n @ Wi1.T (acc 32 regs) ----
        f32x4 accrz[2][2] = {}, acchn[2] = {}, accgn[2] = {};
        #pragma unroll 1
        for (int kc = 0; kc < 8; ++kc) {
            bf16x8 a1[2], an[2];
            a1[0] = *(const bf16x8*)&h1L[rb][abase0 + kc * 32];
            a1[1] = *(const bf16x8*)&h1L[rb][abase1 + kc * 32];
            an[0] = *(const bf16x8*)&h0L[wb][abase0 + kc * 32];
            an[1] = *(const bf16x8*)&h0L[wb][abase1 + kc * 32];
            #pragma unroll
            for (int g = 0; g < 3; ++g) {
                bf16x8 b1 = *(const bf16x8*)(Wh1 + woff[g] + kc * 512);
                #pragma unroll
                for (int i = 0; i < 2; ++i) {
                    if (g < 2) accrz[i][g] = __builtin_amdgcn_mfma_f32_16x16x32_bf16(a1[i], b1, accrz[i][g], 0, 0, 0);
                    else       acchn[i] = __builtin_amdgcn_mfma_f32_16x16x32_bf16(a1[i], b1, acchn[i], 0, 0, 0);
                }
            }
            #pragma unroll
            for (int g = 0; g < 3; ++g) {
                bf16x8 b = *(const bf16x8*)(Wi1 + woff[g] + kc * 512);
                #pragma unroll
                for (int i = 0; i < 2; ++i) {
                    if (g < 2) accrz[i][g] = __builtin_amdgcn_mfma_f32_16x16x32_bf16(an[i], b, accrz[i][g], 0, 0, 0);
                    else       accgn[i] = __builtin_amdgcn_mfma_f32_16x16x32_bf16(an[i], b, accgn[i], 0, 0, 0);
                }
            }
        }
        // ---- layer-1 gates ----
        #pragma unroll
        for (int i = 0; i < 2; ++i)
            #pragma unroll
            for (int r_ = 0; r_ < 4; ++r_) {
                float r = sigm(accrz[i][0][r_] + brr);
                float z = sigm(accrz[i][1][r_] + brz);
                float n = tanh_(accgn[i][r_] + bni + r * (acchn[i][r_] + bnh));
                h1r[i][r_] = n + z * (h1r[i][r_] - n);
            }
        #pragma unroll
        for (int r_ = 0; r_ < 4; ++r_) {
            unsigned u;
            asm("v_cvt_pk_bf16_f32 %0, %1, %2" : "=v"(u) : "v"(h1r[0][r_]), "v"(h1r[1][r_]));
            int ro = hwbase + r_ * HPAD;
            h1L[wb][ro]             = (short)u;
            h1L[wb][ro + 16 * HPAD] = (short)(u >> 16);
        }
        __syncthreads();   // B2: h1n visible

        // ---- packed Y[t] write: wave w -> (mt = w>>3, kc = w&7), one 1KB store ----
        *(bf16x8*)yptr = *(const bf16x8*)&h1L[wb][ybase];
        yptr += (size_t)512 * 8 * 512;

        rb ^= 1; wb ^= 1;
    }
}

// ---- fused head: hdd = relu(Y@W1.T+b1) in LDS, logits = hdd@W2.T+b2 ----
__global__ __launch_bounds__(256) void head_kernel(
    const short* __restrict__ YP, const short* __restrict__ W1P, const float* __restrict__ b1,
    const short* __restrict__ W2P, const float* __restrict__ b2, float* __restrict__ out)
{
    __shared__ short hddL[64 * HPAD];
    int wave = threadIdx.x >> 6;
    int lane = threadIdx.x & 63;
    int quad = lane >> 4;
    int l15  = lane & 15;
    int rbase = blockIdx.x * 64;
    int tt = rbase >> 13;                 // time index (rows = t*8192 + b)
    int mb = (rbase & 8191) >> 4;         // 16-row tile base within t

    { // stage A: hdd tile 64x256; wave w owns n-tiles [w*4, w*4+4)
        const short* ybase = YP + ((size_t)tt * 512 + mb) * 4096 + lane * 8;
        const short* wbase = W1P + (size_t)(wave * 4) * 4096 + lane * 8;
        f32x4 acc[4][4] = {};
        #pragma unroll 2
        for (int kc = 0; kc < 8; ++kc) {
            bf16x8 a[4], bfr[4];
            #pragma unroll
            for (int i = 0; i < 4; ++i) a[i] = *(const bf16x8*)(ybase + (size_t)i * 4096 + kc * 512);
            #pragma unroll
            for (int j = 0; j < 4; ++j) bfr[j] = *(const bf16x8*)(wbase + (size_t)j * 4096 + kc * 512);
            #pragma unroll
            for (int i = 0; i < 4; ++i)
                #pragma unroll
                for (int j = 0; j < 4; ++j)
                    acc[i][j] = __builtin_amdgcn_mfma_f32_16x16x32_bf16(a[i], bfr[j], acc[i][j], 0, 0, 0);
        }
        #pragma unroll
        for (int i = 0; i < 4; ++i)
            #pragma unroll
            for (int j = 0; j < 4; ++j)
                #pragma unroll
                for (int r = 0; r < 4; ++r) {
                    int rl = i * 16 + quad * 4 + r;
                    int c  = wave * 64 + j * 16 + l15;
                    float v = acc[i][j][r] + b1[c];
                    hddL[rl * HPAD + c] = f2b(fmaxf(v, 0.f));
                }
    }
    __syncthreads();
    // stage B: 20 subtiles (10 col-tiles x 2 row-halves) / 4 waves
    for (int s = wave * 5; s < wave * 5 + 5; ++s) {
        int ct = s >> 1, rh = s & 1;
        const short* w2b = W2P + (size_t)ct * 4096 + lane * 8;
        f32x4 acc2[2] = {};
        #pragma unroll 2
        for (int kc = 0; kc < 8; ++kc) {
            bf16x8 bfr = *(const bf16x8*)(w2b + kc * 512);
            #pragma unroll
            for (int it = 0; it < 2; ++it) {
                bf16x8 a = *(const bf16x8*)&hddL[(rh * 32 + it * 16 + l15) * HPAD + kc * 32 + quad * 8];
                acc2[it] = __builtin_amdgcn_mfma_f32_16x16x32_bf16(a, bfr, acc2[it], 0, 0, 0);
            }
        }
        int col = ct * 16 + l15;
        if (col < VOCAB) {
            #pragma unroll
            for (int it = 0; it < 2; ++it)
                #pragma unroll
                for (int r = 0; r < 4; ++r) {
                    int rl = rh * 32 + it * 16 + quad * 4 + r;
                    int gr = rbase + rl;
                    int t2 = gr >> 13;
                    int bb = gr & 8191;
                    out[((size_t)bb * TS + t2) * VOCAB + col] = acc2[it][r] + b2[col];
                }
        }
    }
}

// ---- generated = target_tokens[:,1:] as float ----
__global__ __launch_bounds__(256) void gen_copy(const int* __restrict__ toks, float* __restrict__ out2)
{
    int tid = blockIdx.x * 256 + threadIdx.x;
    if (tid < BATCH * TS) {
        int b = tid / TS, j = tid - b * TS;
        out2[tid] = (float)toks[b * TTOT + j + 1];
    }
}

extern "C" void kernel_launch(void* const* d_in, const int* in_sizes, int n_in,
                              void* d_out, int out_size, void* d_ws, size_t ws_size,
                              hipStream_t stream) {
    const float* z     = (const float*)d_in[0];
    const int*   toks  = (const int*)d_in[1];
    const float* emb   = (const float*)d_in[2];
    const float* W_lat = (const float*)d_in[3];
    const float* b_lat = (const float*)d_in[4];
    const float* W_ih0 = (const float*)d_in[5];
    const float* W_hh0 = (const float*)d_in[6];
    const float* b_ih0 = (const float*)d_in[7];
    const float* b_hh0 = (const float*)d_in[8];
    const float* W_ih1 = (const float*)d_in[9];
    const float* W_hh1 = (const float*)d_in[10];
    const float* b_ih1 = (const float*)d_in[11];
    const float* b_hh1 = (const float*)d_in[12];
    const float* W1    = (const float*)d_in[13];
    const float* b1    = (const float*)d_in[14];
    const float* W2    = (const float*)d_in[15];
    const float* b2    = (const float*)d_in[16];

    char* w = (char*)d_ws;
    short* Yb    = (short*)(w + OFF_Y);
    short* Wh0b  = (short*)(w + OFF_WH0B);
    short* Wi1b  = (short*)(w + OFF_WI1B);
    short* Wh1b  = (short*)(w + OFF_WH1B);
    short* W1b   = (short*)(w + OFF_W1B);
    short* W2b   = (short*)(w + OFF_W2B);
    float* tabrz = (float*)(w + OFF_TAB);
    float* tabn  = (float*)(w + OFF_TABN);
    float* h0f   = (float*)(w + OFF_H0F);
    float* h1f   = (float*)(w + OFF_H1F);

    float* out_logits = (float*)d_out;
    float* out_gen    = out_logits + (size_t)BATCH * TS * VOCAB;

    convert_w<<<2720, 256, 0, stream>>>(W_hh0, W_ih1, W_hh1, W1, W2,
                                        Wh0b, Wi1b, Wh1b, W1b, W2b);
    build_tab2<<<(VOCAB * N3 + 255) / 256, 256, 0, stream>>>(emb, W_ih0, b_ih0, b_hh0, tabrz, tabn);
    init_h<<<(BATCH * 512) / 256, 256, 0, stream>>>(z, W_lat, b_lat, h0f, h1f);
    gen_copy<<<(BATCH * TS + 255) / 256, 256, 0, stream>>>(toks, out_gen);

    gru_persistent<<<256, 1024, 0, stream>>>(toks, tabrz, tabn, Wh0b, Wi1b, Wh1b,
                                             b_hh0, b_ih1, b_hh1, h0f, h1f, Yb);

    head_kernel<<<(BATCH * TS) / 64, 256, 0, stream>>>(Yb, W1b, b1, W2b, b2, out_logits);
}